// Round 14
// baseline (92.466 us; speedup 1.0000x reference)
//
#include <hip/hip_runtime.h>

#define W     768
#define PIX   (768*768)
#define NMAPS 16            // 0..7 anno, 8..15 pred-argmax
#define TROWS 6
#define TPX   (TROWS*W)     // 4608 px per tile
#define NT    (768/TROWS)   // 128 tiles per map
#define NB    (NT-1)        // 127 tile boundaries per map
#define NSEG  (TPX/64)      // 72 wave-segments per tile (12 per row)
#define NIT   (NSEG/4)      // 18 iterations per wave
#define CSLOT 16            // ints per counter slot (64 B line)

// Labels are PACKED everywhere: (label<<2) | cls. Within a component all
// pixels share cls, and min over packed == min over label -> cls bits are
// invariant under atomicMin unions.

__device__ __forceinline__ int find_root_p(volatile int* L, int x) {
    int y = L[x] >> 2;
    while (y != x) { x = y; y = L[x] >> 2; }
    return x;
}

// Unite; true iff a link event occurred (two roots merged). Parents only
// decrease -> acyclic; each index loses rootness at most once, so
// #link events == #merges exactly, independent of atomic ordering.
__device__ __forceinline__ bool unite_p(int* L, int a, int b, int c) {
    volatile int* Lv = L;
    while (true) {
        a = find_root_p(Lv, a);
        b = find_root_p(Lv, b);
        if (a == b) return false;
        if (a > b) { int t = a; a = b; b = t; }
        int old = atomicMin(&L[b], (a << 2) | c);
        if ((old >> 2) == b) return true;
        b = old >> 2;
    }
}

// ---------------- production kernels (R13 structure, unchanged) ----------------

__global__ __launch_bounds__(256) void fused_k(const float* __restrict__ pred,
                                               const int*   __restrict__ anno,
                                               int* __restrict__ labels,
                                               int* __restrict__ counts, int m0) {
    __shared__ int lab[TPX];               // 18 KB packed (label<<2)|cls
    __shared__ int s2[4], s3[4];

    int mc   = blockIdx.x / NT;
    int t    = blockIdx.x - mc * NT;
    int m    = m0 + mc;
    int tid  = threadIdx.x;
    int wid  = tid >> 6;
    int lane = tid & 63;

    unsigned long long lem = (lane == 63) ? ~0ULL : ((2ULL << lane) - 1);  // lanes <= me

    int pc[3] = {0, 0, 0};
    int pm[3] = {0, 0, 0};
    int c2 = 0, c3 = 0;                    // runs - links accumulators

    const int*   asrc = anno + (size_t)m * PIX + (size_t)t * TPX;
    const float* psrc = pred + (size_t)(m < 8 ? 0 : (m - 8)) * 4 * PIX + (size_t)t * TPX;
    bool is_anno = (m < 8);

    int   na = 0;
    float nv0 = 0.f, nv1 = 0.f, nv2 = 0.f, nv3 = 0.f;
    {
        int px = wid * 64 + lane;
        if (is_anno) {
            na = asrc[px];
        } else {
            nv0 = psrc[px];
            nv1 = psrc[(size_t)PIX + px];
            nv2 = psrc[(size_t)2 * PIX + px];
            nv3 = psrc[(size_t)3 * PIX + px];
        }
    }

    #pragma unroll
    for (int it = 0; it < NIT; ++it) {
        int seg = wid + 4 * it;
        int px  = seg * 64 + lane;
        int   ca = na;
        float v0 = nv0, v1 = nv1, v2 = nv2, v3 = nv3;
        if (it + 1 < NIT) {
            int pxn = px + 256;
            if (is_anno) {
                na = asrc[pxn];
            } else {
                nv0 = psrc[pxn];
                nv1 = psrc[(size_t)PIX + pxn];
                nv2 = psrc[(size_t)2 * PIX + pxn];
                nv3 = psrc[(size_t)3 * PIX + pxn];
            }
        }
        int c;
        if (is_anno) {
            c = ca & 3;
        } else {
            c = 0; float bv = v0;           // strict '>' = first-max (jnp.argmax)
            if (v1 > bv) { bv = v1; c = 1; }
            if (v2 > bv) { bv = v2; c = 2; }
            if (v3 > bv) { bv = v3; c = 3; }
        }
        unsigned long long blo = __ballot(c & 1);
        unsigned long long bhi = __ballot(c & 2);
        unsigned long long dif = ((blo ^ (blo << 1)) | (bhi ^ (bhi << 1))) | 1ULL;
        if (lane == 0) {
            c2 += (int)__popcll(dif & bhi & ~blo);
            c3 += (int)__popcll(dif & bhi &  blo);
        }
        int ms = 63 - __clzll(dif & lem);
        lab[px] = ((seg * 64 + ms) << 2) | c;
        const int sl = it % 3;
        if (it >= 3) {
            if ((c & 2) && c == pc[sl]) {
                int mx = ms > pm[sl] ? ms : pm[sl];
                if (lane == mx && unite_p(lab, px - W, px, c)) {
                    if (c == 2) c2--; else c3--;
                }
            }
        }
        pc[sl] = c; pm[sl] = ms;
    }
    __syncthreads();

    if (tid < TROWS * 11) {
        int row = tid / 11, j = tid % 11;
        int px  = row * W + (j + 1) * 64;
        int v = lab[px], c = v & 3;
        if (c & 2) {
            int vl = lab[px - 1];
            if ((vl & 3) == c && unite_p(lab, px - 1, px, c)) {
                if (c == 2) c2--; else c3--;
            }
        }
    }
    __syncthreads();

    int lbase = t * TPX;
    int* gl = labels + (size_t)mc * PIX + lbase;
    #pragma unroll
    for (int q = 0; q < 6; ++q) {
        int it  = (q < 3) ? q : (NIT - 6 + q);   // 0,1,2,15,16,17
        int seg = wid + 4 * it;
        int px  = seg * 64 + lane;
        int v   = lab[px];
        int c   = v & 3;
        int r   = px;
        if (c & 2) r = find_root_p(lab, px);
        int rl = __shfl_up(r, 1);
        gl[px] = ((lbase + r) << 2) | c;
        if ((c & 2) && (lane == 0 || rl != r))
            gl[r] = ((lbase + r) << 2) | c;
    }
    for (int off = 32; off; off >>= 1) {
        c2 += __shfl_down(c2, off, 64);
        c3 += __shfl_down(c3, off, 64);
    }
    if (lane == 0) { s2[wid] = c2; s3[wid] = c3; }
    __syncthreads();
    if (tid == 0) {
        int t2 = s2[0] + s2[1] + s2[2] + s2[3];
        int t3 = s3[0] + s3[1] + s3[2] + s3[3];
        if (t2) atomicAdd(&counts[(m * 2 + 0) * CSLOT], t2);
        if (t3) atomicAdd(&counts[(m * 2 + 1) * CSLOT], t3);
    }
}

__global__ __launch_bounds__(256) void boundary_k(int* __restrict__ labels,
                                                  int* __restrict__ counts, int m0) {
    __shared__ int s2[4], s3[4];
    const int HM = NB * (W / 2);
    int i    = blockIdx.x * 256 + threadIdx.x;
    int mc   = blockIdx.y;
    int m    = m0 + mc;
    int lane = threadIdx.x & 63;

    int m2 = 0, m3 = 0;
    if (i < HM) {
        int b   = i / (W / 2);
        int col = (i - b * (W / 2)) * 2;
        int* L  = labels + (size_t)mc * PIX;
        int p1  = b * TPX + (TROWS - 1) * W + col;
        int p2  = p1 + W;
        int2 va = *(const int2*)&L[p1];
        int2 vb = *(const int2*)&L[p2];
        int pay = __shfl_up(va.y, 1), pby = __shfl_up(vb.y, 1);
        int c0 = va.x & 3;
        if (c0 == (vb.x & 3) && (c0 & 2)) {
            bool red = (lane > 0) && (pay == va.x) && (pby == vb.x);
            if (!red && unite_p(L, p1, p2, c0)) { if (c0 == 2) m2++; else m3++; }
        }
        int c1 = va.y & 3;
        if (c1 == (vb.y & 3) && (c1 & 2)) {
            bool red = (va.x == va.y) && (vb.x == vb.y);
            if (!red && unite_p(L, p1 + 1, p2 + 1, c1)) { if (c1 == 2) m2++; else m3++; }
        }
    }
    for (int off = 32; off; off >>= 1) {
        m2 += __shfl_down(m2, off, 64);
        m3 += __shfl_down(m3, off, 64);
    }
    int wid = threadIdx.x >> 6;
    if (lane == 0) { s2[wid] = m2; s3[wid] = m3; }
    __syncthreads();
    if (threadIdx.x == 0) {
        int t2 = s2[0] + s2[1] + s2[2] + s2[3];
        int t3 = s3[0] + s3[1] + s3[2] + s3[3];
        if (t2) atomicSub(&counts[(m * 2 + 0) * CSLOT], t2);
        if (t3) atomicSub(&counts[(m * 2 + 1) * CSLOT], t3);
    }
}

__global__ void final_k(const int* __restrict__ counts, float* __restrict__ out) {
    float s = 0.0f;
    for (int b = 0; b < 8; ++b) {
        float a2 = (float)counts[(b * 2 + 0) * CSLOT];
        float a3 = (float)counts[(b * 2 + 1) * CSLOT];
        float p2 = (float)counts[((8 + b) * 2 + 0) * CSLOT];
        float p3 = (float)counts[((8 + b) * 2 + 1) * CSLOT];
        float t2 = 1.0f - 2.0f * fminf(p2, a2) / (a2 + p2);
        float t3 = 1.0f - 2.0f * fminf(p3, a3) / (a3 + p3);
        s += t2 + t3;
    }
    out[0] = 0.5f * s;
}

// ---------------- ablation probes (2 pred maps, run after production) ----------------
// probe_load_k: ONLY the phase-A global loads + argmax decode, values kept
// live via asm (rule #17); no LDS, no stores, no ballots.
__global__ __launch_bounds__(256) void probe_load_k(const float* __restrict__ pred) {
    int mc   = blockIdx.x / NT;
    int t    = blockIdx.x - mc * NT;
    int tid  = threadIdx.x;
    int wid  = tid >> 6;
    int lane = tid & 63;
    const float* psrc = pred + (size_t)mc * 4 * PIX + (size_t)t * TPX;

    float nv0, nv1, nv2, nv3;
    {
        int px = wid * 64 + lane;
        nv0 = psrc[px];
        nv1 = psrc[(size_t)PIX + px];
        nv2 = psrc[(size_t)2 * PIX + px];
        nv3 = psrc[(size_t)3 * PIX + px];
    }
    int sum = 0;
    #pragma unroll
    for (int it = 0; it < NIT; ++it) {
        int px = (wid + 4 * it) * 64 + lane;
        float v0 = nv0, v1 = nv1, v2 = nv2, v3 = nv3;
        if (it + 1 < NIT) {
            int pxn = px + 256;
            nv0 = psrc[pxn];
            nv1 = psrc[(size_t)PIX + pxn];
            nv2 = psrc[(size_t)2 * PIX + pxn];
            nv3 = psrc[(size_t)3 * PIX + pxn];
        }
        int c = 0; float bv = v0;
        if (v1 > bv) { bv = v1; c = 1; }
        if (v2 > bv) { bv = v2; c = 2; }
        if (v3 > bv) { bv = v3; c = 3; }
        sum += c;
    }
    asm volatile("" :: "v"(sum));          // keep whole chain live, no output
}

// probe_pa_k: full phase A + stitch (ballots, LDS writes, unions) but no
// phase 3 and no global writes; accumulators kept live via asm.
__global__ __launch_bounds__(256) void probe_pa_k(const float* __restrict__ pred) {
    __shared__ int lab[TPX];
    int mc   = blockIdx.x / NT;
    int t    = blockIdx.x - mc * NT;
    int tid  = threadIdx.x;
    int wid  = tid >> 6;
    int lane = tid & 63;
    unsigned long long lem = (lane == 63) ? ~0ULL : ((2ULL << lane) - 1);
    int pc[3] = {0, 0, 0};
    int pm[3] = {0, 0, 0};
    int c2 = 0, c3 = 0;
    const float* psrc = pred + (size_t)mc * 4 * PIX + (size_t)t * TPX;

    float nv0, nv1, nv2, nv3;
    {
        int px = wid * 64 + lane;
        nv0 = psrc[px];
        nv1 = psrc[(size_t)PIX + px];
        nv2 = psrc[(size_t)2 * PIX + px];
        nv3 = psrc[(size_t)3 * PIX + px];
    }
    #pragma unroll
    for (int it = 0; it < NIT; ++it) {
        int seg = wid + 4 * it;
        int px  = seg * 64 + lane;
        float v0 = nv0, v1 = nv1, v2 = nv2, v3 = nv3;
        if (it + 1 < NIT) {
            int pxn = px + 256;
            nv0 = psrc[pxn];
            nv1 = psrc[(size_t)PIX + pxn];
            nv2 = psrc[(size_t)2 * PIX + pxn];
            nv3 = psrc[(size_t)3 * PIX + pxn];
        }
        int c = 0; float bv = v0;
        if (v1 > bv) { bv = v1; c = 1; }
        if (v2 > bv) { bv = v2; c = 2; }
        if (v3 > bv) { bv = v3; c = 3; }
        unsigned long long blo = __ballot(c & 1);
        unsigned long long bhi = __ballot(c & 2);
        unsigned long long dif = ((blo ^ (blo << 1)) | (bhi ^ (bhi << 1))) | 1ULL;
        if (lane == 0) {
            c2 += (int)__popcll(dif & bhi & ~blo);
            c3 += (int)__popcll(dif & bhi &  blo);
        }
        int ms = 63 - __clzll(dif & lem);
        lab[px] = ((seg * 64 + ms) << 2) | c;
        const int sl = it % 3;
        if (it >= 3) {
            if ((c & 2) && c == pc[sl]) {
                int mx = ms > pm[sl] ? ms : pm[sl];
                if (lane == mx && unite_p(lab, px - W, px, c)) {
                    if (c == 2) c2--; else c3--;
                }
            }
        }
        pc[sl] = c; pm[sl] = ms;
    }
    __syncthreads();
    if (tid < TROWS * 11) {
        int row = tid / 11, j = tid % 11;
        int px  = row * W + (j + 1) * 64;
        int v = lab[px], c = v & 3;
        if (c & 2) {
            int vl = lab[px - 1];
            if ((vl & 3) == c && unite_p(lab, px - 1, px, c)) {
                if (c == 2) c2--; else c3--;
            }
        }
    }
    __syncthreads();
    int z = lab[(tid * 17) & (TPX - 1)];   // dynamic read keeps lab stores live
    asm volatile("" :: "v"(c2), "v"(c3), "v"(z));
}

// ---------------- launch ----------------

extern "C" void kernel_launch(void* const* d_in, const int* in_sizes, int n_in,
                              void* d_out, int out_size, void* d_ws, size_t ws_size,
                              hipStream_t stream) {
    const float* pred = (const float*)d_in[0];   // (8,4,1,768,768) f32
    const int*   anno = (const int*)d_in[1];     // (8,1,768,768) i32
    float* out = (float*)d_out;

    int* counts = (int*)d_ws;                    // 32*CSLOT ints = 2 KB
    char* base  = (char*)d_ws + 4096;

    const size_t per_map = (size_t)PIX * 4;      // packed labels only
    size_t avail = (ws_size > 4096) ? ws_size - 4096 : 0;
    int K = (int)(avail / per_map);
    if (K > 8) K = 8;                            // split anno/pred dispatches
    if (K < 1) K = 1;

    hipMemsetAsync(counts, 0, 32 * CSLOT * sizeof(int), stream);

    const int HM = NB * (W / 2);                 // 48768 col-pairs per map
    for (int m0 = 0; m0 < NMAPS; m0 += K) {
        int nm = NMAPS - m0; if (nm > K) nm = K;
        int* labels = (int*)base;
        fused_k   <<<dim3(nm * NT), 256, 0, stream>>>(pred, anno, labels, counts, m0);
        boundary_k<<<dim3((HM + 255) / 256, nm), 256, 0, stream>>>(labels, counts, m0);
    }
    final_k<<<1, 1, 0, stream>>>(counts, out);

    // ---- ablation probes (output-independent, deterministic) ----
    probe_load_k<<<dim3(2 * NT), 256, 0, stream>>>(pred);
    probe_pa_k  <<<dim3(2 * NT), 256, 0, stream>>>(pred);
}

// Round 15
// 59.312 us; speedup vs baseline: 1.5590x; 1.5590x over previous
//
#include <hip/hip_runtime.h>

#define W     768
#define PIX   (768*768)
#define NMAPS 16            // 0..7 anno, 8..15 pred-argmax
#define TROWS 6
#define TPX   (TROWS*W)     // 4608 px per tile
#define NT    (768/TROWS)   // 128 tiles per map
#define NB    (NT-1)        // 127 tile boundaries per map
#define NSEG  (TPX/64)      // 72 wave-segments per tile (12 per row)
#define NIT   (NSEG/4)      // 18 iterations per wave
#define MAXE  1024          // LDS edge-list capacity (random data ~500)
#define CSLOT 16            // ints per counter slot (64 B line)

// Labels are PACKED everywhere: (label<<2) | cls. Within a component all
// pixels share cls, and min over packed == min over label -> cls bits are
// invariant under atomicMin unions.

__device__ __forceinline__ int find_root_p(volatile int* L, int x) {
    int y = L[x] >> 2;
    while (y != x) { x = y; y = L[x] >> 2; }
    return x;
}

// Unite; true iff a link event occurred (two roots merged). Parents only
// decrease -> acyclic; each index loses rootness at most once, so
// #link events == #merges exactly, independent of atomic ordering AND of
// which thread/phase processes the edge.
__device__ __forceinline__ bool unite_p(int* L, int a, int b, int c) {
    volatile int* Lv = L;
    while (true) {
        a = find_root_p(Lv, a);
        b = find_root_p(Lv, b);
        if (a == b) return false;
        if (a > b) { int t = a; a = b; b = t; }
        int old = atomicMin(&L[b], (a << 2) | c);
        if ((old >> 2) == b) return true;
        b = old >> 2;
    }
}

// ---------------- kernels ----------------

// One block per (map, 6-row tile), 256 threads = 4 waves. R14 diagnosis:
// the DS pipe was issue-bound -- divergent unite_p loops inside phase A
// cost ~19 DS issues per iteration per wave. NOW phase A only APPENDS
// edges (atomicAdd slot + packed write = 2 DS issues) to an LDS edge list;
// after the barrier ALL 256 threads process the ~500 edges cooperatively
// (2/thread, all lanes active in lockstep find/atomic instructions).
// Counting is runs - links (popcounts in phase A; unite link events
// decrement, in whichever phase the edge is processed). Edge overflow
// (adversarial inputs) falls back to inline unite -- same final labels
// and counts regardless of path. Phase 3 touches only tile-boundary rows.
__global__ __launch_bounds__(256) void fused_k(const float* __restrict__ pred,
                                               const int*   __restrict__ anno,
                                               int* __restrict__ labels,
                                               int* __restrict__ counts, int m0) {
    __shared__ int lab[TPX];               // 18 KB packed (label<<2)|cls
    __shared__ int elist[MAXE];            //  4 KB edges: (px<<3)|hor<<2|cls
    __shared__ int ecnt;
    __shared__ int s2[4], s3[4];

    int mc   = blockIdx.x / NT;
    int t    = blockIdx.x - mc * NT;
    int m    = m0 + mc;
    int tid  = threadIdx.x;
    int wid  = tid >> 6;
    int lane = tid & 63;

    unsigned long long lem = (lane == 63) ? ~0ULL : ((2ULL << lane) - 1);  // lanes <= me

    int pc[3] = {0, 0, 0};                 // prev-row class per strip slot
    int pm[3] = {0, 0, 0};                 // prev-row run-start lane per slot
    int c2 = 0, c3 = 0;                    // runs - links accumulators

    const int*   asrc = anno + (size_t)m * PIX + (size_t)t * TPX;
    const float* psrc = pred + (size_t)(m < 8 ? 0 : (m - 8)) * 4 * PIX + (size_t)t * TPX;
    bool is_anno = (m < 8);

    if (tid == 0) ecnt = 0;

    // ---- prefetch it=0 ----
    int   na = 0;
    float nv0 = 0.f, nv1 = 0.f, nv2 = 0.f, nv3 = 0.f;
    {
        int px = wid * 64 + lane;
        if (is_anno) {
            na = asrc[px];
        } else {
            nv0 = psrc[px];
            nv1 = psrc[(size_t)PIX + px];
            nv2 = psrc[(size_t)2 * PIX + px];
            nv3 = psrc[(size_t)3 * PIX + px];
        }
    }
    __syncthreads();                       // ecnt=0 visible before appends

    // ---- phase A: decode cls, ballot run-starts (+run counts), APPEND edges ----
    #pragma unroll
    for (int it = 0; it < NIT; ++it) {
        int seg = wid + 4 * it;
        int px  = seg * 64 + lane;
        int   ca = na;
        float v0 = nv0, v1 = nv1, v2 = nv2, v3 = nv3;
        if (it + 1 < NIT) {
            int pxn = px + 256;
            if (is_anno) {
                na = asrc[pxn];
            } else {
                nv0 = psrc[pxn];
                nv1 = psrc[(size_t)PIX + pxn];
                nv2 = psrc[(size_t)2 * PIX + pxn];
                nv3 = psrc[(size_t)3 * PIX + pxn];
            }
        }
        int c;
        if (is_anno) {
            c = ca & 3;
        } else {
            c = 0; float bv = v0;           // strict '>' = first-max (jnp.argmax)
            if (v1 > bv) { bv = v1; c = 1; }
            if (v2 > bv) { bv = v2; c = 2; }
            if (v3 > bv) { bv = v3; c = 3; }
        }
        unsigned long long blo = __ballot(c & 1);
        unsigned long long bhi = __ballot(c & 2);
        unsigned long long dif = ((blo ^ (blo << 1)) | (bhi ^ (bhi << 1))) | 1ULL;
        if (lane == 0) {
            c2 += (int)__popcll(dif & bhi & ~blo);
            c3 += (int)__popcll(dif & bhi &  blo);
        }
        int ms = 63 - __clzll(dif & lem);
        lab[px] = ((seg * 64 + ms) << 2) | c;
        const int sl = it % 3;
        if (it >= 3) {                      // row >= 1: vertical run-pair edge
            if ((c & 2) && c == pc[sl]) {
                int mx = ms > pm[sl] ? ms : pm[sl];
                if (lane == mx) {
                    int slot = atomicAdd(&ecnt, 1);
                    if (slot < MAXE) {
                        elist[slot] = (px << 3) | c;            // vertical
                    } else if (unite_p(lab, px - W, px, c)) {   // overflow path
                        if (c == 2) c2--; else c3--;
                    }
                }
            }
        }
        pc[sl] = c; pm[sl] = ms;
    }
    __syncthreads();

    // ---- stitch append: 66 cross-strip horizontal edges ----
    if (tid < TROWS * 11) {
        int row = tid / 11, j = tid % 11;
        int px  = row * W + (j + 1) * 64;
        int v = lab[px], c = v & 3;
        if (c & 2) {
            int vl = lab[px - 1];
            if ((vl & 3) == c) {
                int slot = atomicAdd(&ecnt, 1);
                if (slot < MAXE) {
                    elist[slot] = (px << 3) | 4 | c;            // horizontal
                } else if (unite_p(lab, px - 1, px, c)) {
                    if (c == 2) c2--; else c3--;
                }
            }
        }
    }
    __syncthreads();

    // ---- union phase: all 256 threads over the edge list ----
    {
        int ne = ecnt; if (ne > MAXE) ne = MAXE;
        for (int i = tid; i < ne; i += 256) {
            int e  = elist[i];
            int px = e >> 3;
            int c  = e & 3;
            int a  = (e & 4) ? px - 1 : px - W;
            if (unite_p(lab, a, px, c)) {
                if (c == 2) c2--; else c3--;
            }
        }
    }
    __syncthreads();

    // ---- phase 3: ONLY tile-boundary rows: find + compressed write +
    //      boundary-reachable root self-pointers (shfl-deduped) ----
    int lbase = t * TPX;                    // map-local base of this tile
    int* gl = labels + (size_t)mc * PIX + lbase;
    #pragma unroll
    for (int q = 0; q < 6; ++q) {
        int it  = (q < 3) ? q : (NIT - 6 + q);   // 0,1,2,15,16,17
        int seg = wid + 4 * it;
        int px  = seg * 64 + lane;
        int v   = lab[px];
        int c   = v & 3;
        int r   = px;
        if (c & 2) r = find_root_p(lab, px);
        int rl = __shfl_up(r, 1);
        gl[px] = ((lbase + r) << 2) | c;         // compressed label (or self)
        if ((c & 2) && (lane == 0 || rl != r))
            gl[r] = ((lbase + r) << 2) | c;      // root self-pointer (idempotent)
    }
    // reduce (runs - links) -> one padded atomic per (block, class)
    for (int off = 32; off; off >>= 1) {
        c2 += __shfl_down(c2, off, 64);
        c3 += __shfl_down(c3, off, 64);
    }
    if (lane == 0) { s2[wid] = c2; s3[wid] = c3; }
    __syncthreads();
    if (tid == 0) {
        int t2 = s2[0] + s2[1] + s2[2] + s2[3];
        int t3 = s3[0] + s3[1] + s3[2] + s3[3];
        if (t2) atomicAdd(&counts[(m * 2 + 0) * CSLOT], t2);
        if (t3) atomicAdd(&counts[(m * 2 + 1) * CSLOT], t3);
    }
}

// Cross-tile boundary edges on packed labels, 2 columns per thread (int2).
// Run-dedup via shfl; duplicate unions are idempotent and count only real
// merges. blockIdx.y = map -> counts index is block-uniform.
__global__ __launch_bounds__(256) void boundary_k(int* __restrict__ labels,
                                                  int* __restrict__ counts, int m0) {
    __shared__ int s2[4], s3[4];
    const int HM = NB * (W / 2);               // 48768 col-pairs per map
    int i    = blockIdx.x * 256 + threadIdx.x;
    int mc   = blockIdx.y;
    int m    = m0 + mc;
    int lane = threadIdx.x & 63;

    int m2 = 0, m3 = 0;
    if (i < HM) {
        int b   = i / (W / 2);
        int col = (i - b * (W / 2)) * 2;
        int* L  = labels + (size_t)mc * PIX;
        int p1  = b * TPX + (TROWS - 1) * W + col;   // tile b, last row
        int p2  = p1 + W;                            // tile b+1, row 0
        int2 va = *(const int2*)&L[p1];
        int2 vb = *(const int2*)&L[p2];
        int pay = __shfl_up(va.y, 1), pby = __shfl_up(vb.y, 1);
        int c0 = va.x & 3;
        if (c0 == (vb.x & 3) && (c0 & 2)) {
            bool red = (lane > 0) && (pay == va.x) && (pby == vb.x);
            if (!red && unite_p(L, p1, p2, c0)) { if (c0 == 2) m2++; else m3++; }
        }
        int c1 = va.y & 3;
        if (c1 == (vb.y & 3) && (c1 & 2)) {
            bool red = (va.x == va.y) && (vb.x == vb.y);
            if (!red && unite_p(L, p1 + 1, p2 + 1, c1)) { if (c1 == 2) m2++; else m3++; }
        }
    }
    for (int off = 32; off; off >>= 1) {
        m2 += __shfl_down(m2, off, 64);
        m3 += __shfl_down(m3, off, 64);
    }
    int wid = threadIdx.x >> 6;
    if (lane == 0) { s2[wid] = m2; s3[wid] = m3; }
    __syncthreads();
    if (threadIdx.x == 0) {
        int t2 = s2[0] + s2[1] + s2[2] + s2[3];
        int t3 = s3[0] + s3[1] + s3[2] + s3[3];
        if (t2) atomicSub(&counts[(m * 2 + 0) * CSLOT], t2);
        if (t3) atomicSub(&counts[(m * 2 + 1) * CSLOT], t3);
    }
}

__global__ void final_k(const int* __restrict__ counts, float* __restrict__ out) {
    float s = 0.0f;
    for (int b = 0; b < 8; ++b) {
        float a2 = (float)counts[(b * 2 + 0) * CSLOT];
        float a3 = (float)counts[(b * 2 + 1) * CSLOT];
        float p2 = (float)counts[((8 + b) * 2 + 0) * CSLOT];
        float p3 = (float)counts[((8 + b) * 2 + 1) * CSLOT];
        float t2 = 1.0f - 2.0f * fminf(p2, a2) / (a2 + p2);
        float t3 = 1.0f - 2.0f * fminf(p3, a3) / (a3 + p3);
        s += t2 + t3;
    }
    out[0] = 0.5f * s;
}

// ---------------- launch ----------------

extern "C" void kernel_launch(void* const* d_in, const int* in_sizes, int n_in,
                              void* d_out, int out_size, void* d_ws, size_t ws_size,
                              hipStream_t stream) {
    const float* pred = (const float*)d_in[0];   // (8,4,1,768,768) f32
    const int*   anno = (const int*)d_in[1];     // (8,1,768,768) i32
    float* out = (float*)d_out;

    int* counts = (int*)d_ws;                    // 32*CSLOT ints = 2 KB
    char* base  = (char*)d_ws + 4096;

    const size_t per_map = (size_t)PIX * 4;      // packed labels only
    size_t avail = (ws_size > 4096) ? ws_size - 4096 : 0;
    int K = (int)(avail / per_map);
    if (K > NMAPS) K = NMAPS;
    if (K < 1)     K = 1;    // best effort; needs ~2.4 MB min

    hipMemsetAsync(counts, 0, 32 * CSLOT * sizeof(int), stream);

    const int HM = NB * (W / 2);                 // 48768 col-pairs per map
    for (int m0 = 0; m0 < NMAPS; m0 += K) {
        int nm = NMAPS - m0; if (nm > K) nm = K;
        int* labels = (int*)base;
        fused_k   <<<dim3(nm * NT), 256, 0, stream>>>(pred, anno, labels, counts, m0);
        boundary_k<<<dim3((HM + 255) / 256, nm), 256, 0, stream>>>(labels, counts, m0);
    }
    final_k<<<1, 1, 0, stream>>>(counts, out);
}